// Round 1
// baseline (1013.597 us; speedup 1.0000x reference)
//
#include <hip/hip_runtime.h>
#include <hip/hip_bf16.h>
#include <math.h>

#define N_EDGES_C 320000
#define N_PART 10000
#define EMBED 256
#define NRBF 16
#define OUTE 512

// ---------------------------------------------------------------------------
// Stage 1: gated = messages * (rbf @ W_rbf); scatter-add into summed[idx_i]
// One column per thread (256 threads = 256 embed cols), grid-stride over edges.
// W_rbf (16x256 = 16 KB) staged in LDS; rbf[e][k] and idx_i[e] are wave-uniform
// -> scalar loads. messages read coalesced (1 KB/edge across the block).
// ---------------------------------------------------------------------------
__global__ __launch_bounds__(256) void edge_gate_scatter(
    const float* __restrict__ messages, const float* __restrict__ rbf,
    const int* __restrict__ idx_i, const float* __restrict__ W_rbf,
    float* __restrict__ summed)
{
    __shared__ float w[NRBF][EMBED];
    const int c = threadIdx.x;
#pragma unroll
    for (int k = 0; k < NRBF; ++k) w[k][c] = W_rbf[k * EMBED + c];
    __syncthreads();

    for (int e = blockIdx.x; e < N_EDGES_C; e += gridDim.x) {
        const int p = idx_i[e];
        float t = 0.f;
#pragma unroll
        for (int k = 0; k < NRBF; ++k)
            t = fmaf(rbf[(size_t)e * NRBF + k], w[k][c], t);
        const float g = messages[(size_t)e * EMBED + c] * t;
        atomicAdd(&summed[(size_t)p * EMBED + c], g);
    }
}

// ---------------------------------------------------------------------------
// fp32 tiled GEMM: C[M,N] = act(A[M,K] @ B[K,N] + bias), row-major.
// 64x64 tile, BK=32, 256 threads, 4x4 micro-tile per thread.
// ACT: 0 = identity, 1 = swish (x*sigmoid(x)).
// K multiple of 32, N multiple of 64; M may be ragged (guarded).
// ---------------------------------------------------------------------------
template <int ACT>
__global__ __launch_bounds__(256) void gemm_bias_act(
    const float* __restrict__ A, const float* __restrict__ B,
    const float* __restrict__ bias, float* __restrict__ C,
    int M, int K, int N)
{
    __shared__ float As[32][64 + 1];  // As[k][m]
    __shared__ float Bs[32][64 + 1];  // Bs[k][n]

    const int tid = threadIdx.x;
    const int bm = blockIdx.x * 64;
    const int bn = blockIdx.y * 64;
    const int tm = (tid >> 4) * 4;   // 0..60
    const int tn = (tid & 15) * 4;   // 0..60

    const int ar = tid >> 5;   // 0..7   (A: 8 rows/pass, 32 k-cols)
    const int ac = tid & 31;   // 0..31
    const int br = tid >> 6;   // 0..3   (B: 4 k-rows/pass, 64 n-cols)
    const int bc = tid & 63;   // 0..63

    float acc[4][4] = {};

    for (int k0 = 0; k0 < K; k0 += 32) {
#pragma unroll
        for (int p = 0; p < 8; ++p) {
            const int m = bm + ar + p * 8;
            As[ac][ar + p * 8] = (m < M) ? A[(size_t)m * K + k0 + ac] : 0.f;
        }
#pragma unroll
        for (int p = 0; p < 8; ++p) {
            Bs[br + p * 4][bc] = B[(size_t)(k0 + br + p * 4) * N + bn + bc];
        }
        __syncthreads();

#pragma unroll
        for (int k = 0; k < 32; ++k) {
            float a[4], b[4];
#pragma unroll
            for (int i = 0; i < 4; ++i) a[i] = As[k][tm + i];
#pragma unroll
            for (int j = 0; j < 4; ++j) b[j] = Bs[k][tn + j];
#pragma unroll
            for (int i = 0; i < 4; ++i)
#pragma unroll
                for (int j = 0; j < 4; ++j)
                    acc[i][j] = fmaf(a[i], b[j], acc[i][j]);
        }
        __syncthreads();
    }

#pragma unroll
    for (int i = 0; i < 4; ++i) {
        const int m = bm + tm + i;
        if (m >= M) continue;
#pragma unroll
        for (int j = 0; j < 4; ++j) {
            float v = acc[i][j];
            if (bias) v += bias[bn + tn + j];
            if (ACT == 1) v = v * (1.f / (1.f + expf(-v)));
            C[(size_t)m * N + bn + tn + j] = v;
        }
    }
}

// ---------------------------------------------------------------------------
// Final head: out[p] = dot(up[p,:], W_final[:,0]).  One wave per particle.
// ---------------------------------------------------------------------------
__global__ __launch_bounds__(256) void final_dot(
    const float* __restrict__ up, const float* __restrict__ Wf,
    float* __restrict__ out)
{
    const int wave = threadIdx.x >> 6;
    const int lane = threadIdx.x & 63;
    const int p = blockIdx.x * 4 + wave;
    if (p >= N_PART) return;
    float s = 0.f;
#pragma unroll
    for (int k = lane; k < OUTE; k += 64)
        s = fmaf(up[(size_t)p * OUTE + k], Wf[k], s);
#pragma unroll
    for (int off = 32; off > 0; off >>= 1) s += __shfl_down(s, off);
    if (lane == 0) out[p] = s;
}

extern "C" void kernel_launch(void* const* d_in, const int* in_sizes, int n_in,
                              void* d_out, int out_size, void* d_ws, size_t ws_size,
                              hipStream_t stream) {
    const float* messages = (const float*)d_in[0];
    const float* rbf      = (const float*)d_in[1];
    const int*   idx_i    = (const int*)d_in[2];
    const float* W_rbf    = (const float*)d_in[3];
    const float* W_up     = (const float*)d_in[4];
    const float* W_d0     = (const float*)d_in[5];
    const float* b_d0     = (const float*)d_in[6];
    const float* W_d1     = (const float*)d_in[7];
    const float* b_d1     = (const float*)d_in[8];
    const float* W_final  = (const float*)d_in[9];
    float* out = (float*)d_out;

    char* ws = (char*)d_ws;
    float* summed = (float*)ws;                              // 10,240,000 B
    float* buf0   = (float*)(ws + 10240000);                 // 20,480,000 B
    float* buf1   = (float*)(ws + 10240000 + 20480000);      // 20,480,000 B

    hipMemsetAsync(summed, 0, (size_t)N_PART * EMBED * sizeof(float), stream);

    edge_gate_scatter<<<4096, 256, 0, stream>>>(messages, rbf, idx_i, W_rbf, summed);

    dim3 g1((N_PART + 63) / 64, OUTE / 64);  // 157 x 8
    gemm_bias_act<0><<<g1, 256, 0, stream>>>(summed, W_up, nullptr, buf0,
                                             N_PART, EMBED, OUTE);
    gemm_bias_act<1><<<g1, 256, 0, stream>>>(buf0, W_d0, b_d0, buf1,
                                             N_PART, OUTE, OUTE);
    gemm_bias_act<1><<<g1, 256, 0, stream>>>(buf1, W_d1, b_d1, buf0,
                                             N_PART, OUTE, OUTE);

    final_dot<<<(N_PART + 3) / 4, 256, 0, stream>>>(buf0, W_final, out);
}

// Round 2
// 672.996 us; speedup vs baseline: 1.5061x; 1.5061x over previous
//
#include <hip/hip_runtime.h>
#include <hip/hip_bf16.h>
#include <math.h>

#define N_EDGES_C 320000
#define N_PART 10000
#define EMBED 256
#define NRBF 16
#define OUTE 512

typedef __attribute__((ext_vector_type(8))) short short8;
typedef __attribute__((ext_vector_type(4))) float float4v;

// ---------------- workspace layout (bytes; all 16-aligned) ----------------
#define WS_SUMMED   0            // 10000*256*2  = 5,120,000   bf16
#define WS_BUF0     6000000      // 10000*512*2  = 10,240,000  bf16
#define WS_BUF1     17000000     // 10,240,000                  bf16
#define WS_WTUP     28000000     // 512*256*2 = 262,144         bf16 [N][K]
#define WS_WTD0     28300000     // 512*512*2 = 524,288
#define WS_WTD1     28900000     // 524,288
#define WS_CNT      29500000     // 10000*4
#define WS_CUR      29540000     // 10000*4  (contiguous with CNT for one memset)
#define WS_OFF      29580000     // 10000*4
#define WS_ELIST    29640000     // 320000*4

// ---------------------------------------------------------------------------
// CSR build: histogram -> single-block scan -> fill
// ---------------------------------------------------------------------------
__global__ __launch_bounds__(256) void hist_kernel(
    const int* __restrict__ idx_i, int* __restrict__ cnt)
{
    int e = blockIdx.x * 256 + threadIdx.x;
    if (e < N_EDGES_C) atomicAdd(&cnt[idx_i[e]], 1);
}

__global__ __launch_bounds__(256) void scan_kernel(
    const int* __restrict__ cnt, int* __restrict__ off)
{
    __shared__ int s[256];
    const int t = threadIdx.x;
    const int base = t * 40;                 // 256*40 >= 10000
    int v[40];
    int loc = 0;
#pragma unroll
    for (int i = 0; i < 40; ++i) {
        int idx = base + i;
        int c = (idx < N_PART) ? cnt[idx] : 0;
        v[i] = c;
        loc += c;
    }
    s[t] = loc;
    __syncthreads();
    for (int d = 1; d < 256; d <<= 1) {
        int x = (t >= d) ? s[t - d] : 0;
        __syncthreads();
        s[t] += x;
        __syncthreads();
    }
    int pre = (t > 0) ? s[t - 1] : 0;        // exclusive prefix of thread sums
#pragma unroll
    for (int i = 0; i < 40; ++i) {
        int idx = base + i;
        if (idx < N_PART) off[idx] = pre;
        pre += v[i];
    }
}

__global__ __launch_bounds__(256) void fill_kernel(
    const int* __restrict__ idx_i, const int* __restrict__ off,
    int* __restrict__ cur, int* __restrict__ elist)
{
    int e = blockIdx.x * 256 + threadIdx.x;
    if (e >= N_EDGES_C) return;
    int p = idx_i[e];
    int pos = atomicAdd(&cur[p], 1);
    elist[off[p] + pos] = e;
}

// ---------------------------------------------------------------------------
// Gather: one 256-thread block per particle. summed[p][c] =
//   sum_{e in edges(p)} messages[e][c] * dot(rbf[e,:], W_rbf[:,c])
// No atomics; messages rows read coalesced (1 KB contiguous per edge).
// ---------------------------------------------------------------------------
__global__ __launch_bounds__(256) void gather_kernel(
    const float* __restrict__ messages, const float* __restrict__ rbf,
    const float* __restrict__ W_rbf, const int* __restrict__ off,
    const int* __restrict__ cnt, const int* __restrict__ elist,
    __hip_bfloat16* __restrict__ summed)
{
    __shared__ float w[NRBF][EMBED];
    const int c = threadIdx.x;
    const int p = blockIdx.x;
#pragma unroll
    for (int k = 0; k < NRBF; ++k) w[k][c] = W_rbf[k * EMBED + c];
    __syncthreads();

    const int base = off[p];
    const int deg  = cnt[p];
    float acc = 0.f;
    for (int j = 0; j < deg; ++j) {
        const int e = elist[base + j];
        const float4* r4 = (const float4*)(rbf + (size_t)e * NRBF);
        float4 r0 = r4[0], r1 = r4[1], r2 = r4[2], r3 = r4[3];
        float t = 0.f;
        t = fmaf(r0.x, w[0][c], t);  t = fmaf(r0.y, w[1][c], t);
        t = fmaf(r0.z, w[2][c], t);  t = fmaf(r0.w, w[3][c], t);
        t = fmaf(r1.x, w[4][c], t);  t = fmaf(r1.y, w[5][c], t);
        t = fmaf(r1.z, w[6][c], t);  t = fmaf(r1.w, w[7][c], t);
        t = fmaf(r2.x, w[8][c], t);  t = fmaf(r2.y, w[9][c], t);
        t = fmaf(r2.z, w[10][c], t); t = fmaf(r2.w, w[11][c], t);
        t = fmaf(r3.x, w[12][c], t); t = fmaf(r3.y, w[13][c], t);
        t = fmaf(r3.z, w[14][c], t); t = fmaf(r3.w, w[15][c], t);
        acc = fmaf(messages[(size_t)e * EMBED + c], t, acc);
    }
    summed[(size_t)p * EMBED + c] = __float2bfloat16(acc);
}

// ---------------------------------------------------------------------------
// Weight transpose+convert: Wt[n][k] = bf16(W[k][n]). K,N multiples of 32.
// ---------------------------------------------------------------------------
__global__ __launch_bounds__(256) void transpose_cvt(
    const float* __restrict__ W, __hip_bfloat16* __restrict__ Wt, int K, int N)
{
    __shared__ float t[32][33];
    const int bn = blockIdx.x * 32;   // n tile
    const int bk = blockIdx.y * 32;   // k tile
    const int x = threadIdx.x & 31;
    const int y8 = threadIdx.x >> 5;  // 0..7
#pragma unroll
    for (int yy = y8; yy < 32; yy += 8)
        t[yy][x] = W[(size_t)(bk + yy) * N + bn + x];
    __syncthreads();
#pragma unroll
    for (int yy = y8; yy < 32; yy += 8)
        Wt[(size_t)(bn + yy) * K + bk + x] = __float2bfloat16(t[x][yy]);
}

// ---------------------------------------------------------------------------
// bf16 MFMA GEMM: C[M][N] = act(A[M][K] @ Bt[N][K]^T + bias), bf16 in/out,
// fp32 accumulate. 128x128 tile, BK=32, 4 waves, each wave 64x64 via 4x4
// mfma_f32_16x16x32_bf16. LDS pitch 40 bf16 (80 B, 20-bank stride).
// ---------------------------------------------------------------------------
#define BM 128
#define BN 128
#define BK 32
#define LDSP 40

template <int ACT>
__global__ __launch_bounds__(256) void gemm_mfma(
    const __hip_bfloat16* __restrict__ A,   // [M][K]
    const __hip_bfloat16* __restrict__ Bt,  // [N][K]
    const float* __restrict__ bias,          // [N] or null
    __hip_bfloat16* __restrict__ C,          // [M][N]
    int M, int K, int N)
{
    __shared__ short As[BM * LDSP];
    __shared__ short Bs[BN * LDSP];

    const int tid  = threadIdx.x;
    const int bm   = blockIdx.x * BM;
    const int bn   = blockIdx.y * BN;
    const int wave = tid >> 6;
    const int lane = tid & 63;
    const int wm   = (wave >> 1) * 64;
    const int wn   = (wave & 1) * 64;
    const int l16  = lane & 15;
    const int quad = lane >> 4;

    float4v acc[4][4];
#pragma unroll
    for (int i = 0; i < 4; ++i)
#pragma unroll
        for (int j = 0; j < 4; ++j)
#pragma unroll
            for (int r = 0; r < 4; ++r) acc[i][j][r] = 0.f;

    const int sr = tid >> 1;         // staging row 0..127
    const int sh = (tid & 1) * 16;   // staging k-offset 0 / 16

    for (int k0 = 0; k0 < K; k0 += BK) {
        // --- stage A (guard ragged M with zeros) ---
        short8 av0, av1;
        if (bm + sr < M) {
            const short8* ga = (const short8*)((const short*)A + (size_t)(bm + sr) * K + k0 + sh);
            av0 = ga[0];
            av1 = ga[1];
        } else {
#pragma unroll
            for (int i = 0; i < 8; ++i) { av0[i] = 0; av1[i] = 0; }
        }
        *(short8*)&As[sr * LDSP + sh]     = av0;
        *(short8*)&As[sr * LDSP + sh + 8] = av1;
        // --- stage B (N always multiple of 128) ---
        const short8* gb = (const short8*)((const short*)Bt + (size_t)(bn + sr) * K + k0 + sh);
        short8 bv0 = gb[0], bv1 = gb[1];
        *(short8*)&Bs[sr * LDSP + sh]     = bv0;
        *(short8*)&Bs[sr * LDSP + sh + 8] = bv1;
        __syncthreads();

        short8 af[4], bf[4];
#pragma unroll
        for (int mt = 0; mt < 4; ++mt)
            af[mt] = *(const short8*)&As[(wm + mt * 16 + l16) * LDSP + quad * 8];
#pragma unroll
        for (int nt = 0; nt < 4; ++nt)
            bf[nt] = *(const short8*)&Bs[(wn + nt * 16 + l16) * LDSP + quad * 8];
#pragma unroll
        for (int mt = 0; mt < 4; ++mt)
#pragma unroll
            for (int nt = 0; nt < 4; ++nt)
                acc[mt][nt] = __builtin_amdgcn_mfma_f32_16x16x32_bf16(
                    af[mt], bf[nt], acc[mt][nt], 0, 0, 0);
        __syncthreads();
    }

#pragma unroll
    for (int mt = 0; mt < 4; ++mt) {
        const int row0 = bm + wm + mt * 16 + quad * 4;
#pragma unroll
        for (int nt = 0; nt < 4; ++nt) {
            const int col = bn + wn + nt * 16 + l16;
            const float bv = bias ? bias[col] : 0.f;
#pragma unroll
            for (int r = 0; r < 4; ++r) {
                const int rr = row0 + r;
                if (rr < M) {
                    float v = acc[mt][nt][r] + bv;
                    if (ACT == 1) v = v / (1.f + expf(-v));
                    C[(size_t)rr * N + col] = __float2bfloat16(v);
                }
            }
        }
    }
}

// ---------------------------------------------------------------------------
// Final head: out[p] = dot(up[p,:], W_final[:,0]). One wave per particle.
// ---------------------------------------------------------------------------
__global__ __launch_bounds__(256) void final_dot(
    const __hip_bfloat16* __restrict__ up, const float* __restrict__ Wf,
    float* __restrict__ out)
{
    const int wave = threadIdx.x >> 6;
    const int lane = threadIdx.x & 63;
    const int p = blockIdx.x * 4 + wave;
    if (p >= N_PART) return;
    float s = 0.f;
#pragma unroll
    for (int k = lane; k < OUTE; k += 64)
        s = fmaf(__bfloat162float(up[(size_t)p * OUTE + k]), Wf[k], s);
#pragma unroll
    for (int off = 32; off > 0; off >>= 1) s += __shfl_down(s, off);
    if (lane == 0) out[p] = s;
}

extern "C" void kernel_launch(void* const* d_in, const int* in_sizes, int n_in,
                              void* d_out, int out_size, void* d_ws, size_t ws_size,
                              hipStream_t stream) {
    const float* messages = (const float*)d_in[0];
    const float* rbf      = (const float*)d_in[1];
    const int*   idx_i    = (const int*)d_in[2];
    const float* W_rbf    = (const float*)d_in[3];
    const float* W_up     = (const float*)d_in[4];
    const float* W_d0     = (const float*)d_in[5];
    const float* b_d0     = (const float*)d_in[6];
    const float* W_d1     = (const float*)d_in[7];
    const float* b_d1     = (const float*)d_in[8];
    const float* W_final  = (const float*)d_in[9];
    float* out = (float*)d_out;

    char* ws = (char*)d_ws;
    __hip_bfloat16* summed = (__hip_bfloat16*)(ws + WS_SUMMED);
    __hip_bfloat16* buf0   = (__hip_bfloat16*)(ws + WS_BUF0);
    __hip_bfloat16* buf1   = (__hip_bfloat16*)(ws + WS_BUF1);
    __hip_bfloat16* wt_up  = (__hip_bfloat16*)(ws + WS_WTUP);
    __hip_bfloat16* wt_d0  = (__hip_bfloat16*)(ws + WS_WTD0);
    __hip_bfloat16* wt_d1  = (__hip_bfloat16*)(ws + WS_WTD1);
    int* cnt   = (int*)(ws + WS_CNT);
    int* cur   = (int*)(ws + WS_CUR);
    int* offp  = (int*)(ws + WS_OFF);
    int* elist = (int*)(ws + WS_ELIST);

    // zero cnt+cur (contiguous 80 KB)
    hipMemsetAsync(ws + WS_CNT, 0, 80000, stream);

    // CSR build
    hist_kernel<<<(N_EDGES_C + 255) / 256, 256, 0, stream>>>(idx_i, cnt);
    scan_kernel<<<1, 256, 0, stream>>>(cnt, offp);
    fill_kernel<<<(N_EDGES_C + 255) / 256, 256, 0, stream>>>(idx_i, offp, cur, elist);

    // weight transpose+convert (runs independent of CSR; same stream order fine)
    transpose_cvt<<<dim3(OUTE / 32, EMBED / 32), 256, 0, stream>>>(W_up,  wt_up,  EMBED, OUTE);
    transpose_cvt<<<dim3(OUTE / 32, OUTE  / 32), 256, 0, stream>>>(W_d0,  wt_d0,  OUTE,  OUTE);
    transpose_cvt<<<dim3(OUTE / 32, OUTE  / 32), 256, 0, stream>>>(W_d1,  wt_d1,  OUTE,  OUTE);

    // gather (no atomics)
    gather_kernel<<<N_PART, 256, 0, stream>>>(messages, rbf, W_rbf, offp, cnt,
                                              elist, summed);

    // MLP via bf16 MFMA GEMMs
    dim3 g((N_PART + BM - 1) / BM, OUTE / BN);  // 79 x 4
    gemm_mfma<0><<<g, 256, 0, stream>>>(summed, wt_up, nullptr, buf0,
                                        N_PART, EMBED, OUTE);
    gemm_mfma<1><<<g, 256, 0, stream>>>(buf0, wt_d0, b_d0, buf1,
                                        N_PART, OUTE, OUTE);
    gemm_mfma<1><<<g, 256, 0, stream>>>(buf1, wt_d1, b_d1, buf0,
                                        N_PART, OUTE, OUTE);

    final_dot<<<(N_PART + 3) / 4, 256, 0, stream>>>(buf0, W_final, out);
}

// Round 3
// 625.902 us; speedup vs baseline: 1.6194x; 1.0752x over previous
//
#include <hip/hip_runtime.h>
#include <hip/hip_bf16.h>
#include <math.h>

#define N_EDGES_C 320000
#define N_PART 10000
#define EMBED 256
#define NRBF 16
#define OUTE 512

typedef __attribute__((ext_vector_type(8))) short short8;
typedef __attribute__((ext_vector_type(4))) float float4v;

// ---------------- workspace layout (bytes; all 16-aligned) ----------------
#define WS_SUMMED   0            // 10000*256*2  = 5,120,000   bf16
#define WS_BUF0     6000000      // 10000*512*2  = 10,240,000  bf16
#define WS_BUF1     17000000     // 10,240,000                  bf16
#define WS_WTUP     28000000     // 512*256*2 = 262,144         bf16 [N][K]
#define WS_WTD0     28300000     // 512*512*2 = 524,288
#define WS_WTD1     28900000     // 524,288
#define WS_CNT      29500000     // 10000*4
#define WS_CUR      29540000     // 10000*4  (contiguous with CNT for one memset)
#define WS_OFF      29580000     // 10000*4
#define WS_ELIST    29640000     // 320000*4

// ---------------------------------------------------------------------------
// CSR build: histogram -> single-block scan (1024 thr) -> fill
// ---------------------------------------------------------------------------
__global__ __launch_bounds__(256) void hist_kernel(
    const int* __restrict__ idx_i, int* __restrict__ cnt)
{
    int e = blockIdx.x * 256 + threadIdx.x;
    if (e < N_EDGES_C) atomicAdd(&cnt[idx_i[e]], 1);
}

__global__ __launch_bounds__(1024) void scan_kernel(
    const int* __restrict__ cnt, int* __restrict__ off)
{
    __shared__ int s[1024];
    const int t = threadIdx.x;
    const int base = t * 10;                 // 1024*10 >= 10000
    int v[10];
    int loc = 0;
#pragma unroll
    for (int i = 0; i < 10; ++i) {
        int idx = base + i;
        int c = (idx < N_PART) ? cnt[idx] : 0;
        v[i] = c;
        loc += c;
    }
    s[t] = loc;
    __syncthreads();
    for (int d = 1; d < 1024; d <<= 1) {
        int x = (t >= d) ? s[t - d] : 0;
        __syncthreads();
        s[t] += x;
        __syncthreads();
    }
    int pre = (t > 0) ? s[t - 1] : 0;        // exclusive prefix of thread sums
#pragma unroll
    for (int i = 0; i < 10; ++i) {
        int idx = base + i;
        if (idx < N_PART) off[idx] = pre;
        pre += v[i];
    }
}

__global__ __launch_bounds__(256) void fill_kernel(
    const int* __restrict__ idx_i, const int* __restrict__ off,
    int* __restrict__ cur, int* __restrict__ elist)
{
    int e = blockIdx.x * 256 + threadIdx.x;
    if (e >= N_EDGES_C) return;
    int p = idx_i[e];
    int pos = atomicAdd(&cur[p], 1);
    elist[off[p] + pos] = e;
}

// ---------------------------------------------------------------------------
// Gather v2: one 256-thread block per particle, thread = embed column.
// Edge list staged in LDS; edge loop unrolled x4 so four 1-KB messages-row
// loads are in flight per wave (breaks the serial elist->messages chain).
// ---------------------------------------------------------------------------
__device__ __forceinline__ float rbf_gate(
    const float* __restrict__ rbf, int e, const float (*w)[EMBED], int c)
{
    const float4* r4 = (const float4*)(rbf + (size_t)e * NRBF);
    float4 r0 = r4[0], r1 = r4[1], r2 = r4[2], r3 = r4[3];
    float t = 0.f;
    t = fmaf(r0.x, w[0][c], t);  t = fmaf(r0.y, w[1][c], t);
    t = fmaf(r0.z, w[2][c], t);  t = fmaf(r0.w, w[3][c], t);
    t = fmaf(r1.x, w[4][c], t);  t = fmaf(r1.y, w[5][c], t);
    t = fmaf(r1.z, w[6][c], t);  t = fmaf(r1.w, w[7][c], t);
    t = fmaf(r2.x, w[8][c], t);  t = fmaf(r2.y, w[9][c], t);
    t = fmaf(r2.z, w[10][c], t); t = fmaf(r2.w, w[11][c], t);
    t = fmaf(r3.x, w[12][c], t); t = fmaf(r3.y, w[13][c], t);
    t = fmaf(r3.z, w[14][c], t); t = fmaf(r3.w, w[15][c], t);
    return t;
}

__global__ __launch_bounds__(256) void gather_kernel(
    const float* __restrict__ messages, const float* __restrict__ rbf,
    const float* __restrict__ W_rbf, const int* __restrict__ off,
    const int* __restrict__ cnt, const int* __restrict__ elist,
    __hip_bfloat16* __restrict__ summed)
{
    __shared__ float w[NRBF][EMBED];
    __shared__ int el[256];
    const int c = threadIdx.x;
    const int p = blockIdx.x;
#pragma unroll
    for (int k = 0; k < NRBF; ++k) w[k][c] = W_rbf[k * EMBED + c];

    const int base = off[p];
    const int deg  = cnt[p];
    float acc = 0.f;

    for (int ch = 0; ch < deg; ch += 256) {
        const int n = min(256, deg - ch);
        if (c < n) el[c] = elist[base + ch + c];
        __syncthreads();

        int j = 0;
        for (; j + 4 <= n; j += 4) {
            const int e0 = el[j], e1 = el[j + 1], e2 = el[j + 2], e3 = el[j + 3];
            // issue the four heavy loads first (independent, 256 B/wave each)
            const float m0 = messages[(size_t)e0 * EMBED + c];
            const float m1 = messages[(size_t)e1 * EMBED + c];
            const float m2 = messages[(size_t)e2 * EMBED + c];
            const float m3 = messages[(size_t)e3 * EMBED + c];
            const float t0 = rbf_gate(rbf, e0, w, c);
            const float t1 = rbf_gate(rbf, e1, w, c);
            const float t2 = rbf_gate(rbf, e2, w, c);
            const float t3 = rbf_gate(rbf, e3, w, c);
            acc = fmaf(m0, t0, acc);
            acc = fmaf(m1, t1, acc);
            acc = fmaf(m2, t2, acc);
            acc = fmaf(m3, t3, acc);
        }
        for (; j < n; ++j) {
            const int e = el[j];
            const float m = messages[(size_t)e * EMBED + c];
            acc = fmaf(m, rbf_gate(rbf, e, w, c), acc);
        }
        __syncthreads();
    }
    summed[(size_t)p * EMBED + c] = __float2bfloat16(acc);
}

// ---------------------------------------------------------------------------
// Weight transpose+convert, all three weights in one launch (z = which).
// Wt[n][k] = bf16(W[k][n]).
// ---------------------------------------------------------------------------
__global__ __launch_bounds__(256) void transpose_cvt_all(
    const float* __restrict__ W_up, const float* __restrict__ W_d0,
    const float* __restrict__ W_d1, __hip_bfloat16* __restrict__ wt_up,
    __hip_bfloat16* __restrict__ wt_d0, __hip_bfloat16* __restrict__ wt_d1)
{
    const int z = blockIdx.z;
    const float* W = (z == 0) ? W_up : (z == 1) ? W_d0 : W_d1;
    __hip_bfloat16* Wt = (z == 0) ? wt_up : (z == 1) ? wt_d0 : wt_d1;
    const int K = (z == 0) ? EMBED : OUTE;
    const int N = OUTE;
    if (blockIdx.y * 32 >= K) return;

    __shared__ float t[32][33];
    const int bn = blockIdx.x * 32;
    const int bk = blockIdx.y * 32;
    const int x = threadIdx.x & 31;
    const int y8 = threadIdx.x >> 5;
#pragma unroll
    for (int yy = y8; yy < 32; yy += 8)
        t[yy][x] = W[(size_t)(bk + yy) * N + bn + x];
    __syncthreads();
#pragma unroll
    for (int yy = y8; yy < 32; yy += 8)
        Wt[(size_t)(bn + yy) * K + bk + x] = __float2bfloat16(t[x][yy]);
}

// ---------------------------------------------------------------------------
// bf16 MFMA GEMM: 128x128 tile, BK=32, 4 waves, 4x4 mfma_f32_16x16x32_bf16
// per wave. FUSE=1: don't store C; instead out[row] += swish(v) * Wf[col]
// (shfl-reduce over the 16-lane row group, one fp32 atomicAdd per row).
// ---------------------------------------------------------------------------
#define BM 128
#define BN 128
#define BK 32
#define LDSP 40

template <int ACT, int FUSE>
__global__ __launch_bounds__(256) void gemm_mfma(
    const __hip_bfloat16* __restrict__ A,   // [M][K]
    const __hip_bfloat16* __restrict__ Bt,  // [N][K]
    const float* __restrict__ bias,          // [N] or null
    __hip_bfloat16* __restrict__ C,          // [M][N]   (FUSE=0)
    const float* __restrict__ Wf,            // [N]      (FUSE=1)
    float* __restrict__ out,                 // [M]      (FUSE=1)
    int M, int K, int N)
{
    __shared__ short As[BM * LDSP];
    __shared__ short Bs[BN * LDSP];

    const int tid  = threadIdx.x;
    const int bm   = blockIdx.x * BM;
    const int bn   = blockIdx.y * BN;
    const int wave = tid >> 6;
    const int lane = tid & 63;
    const int wm   = (wave >> 1) * 64;
    const int wn   = (wave & 1) * 64;
    const int l16  = lane & 15;
    const int quad = lane >> 4;

    float4v acc[4][4];
#pragma unroll
    for (int i = 0; i < 4; ++i)
#pragma unroll
        for (int j = 0; j < 4; ++j)
#pragma unroll
            for (int r = 0; r < 4; ++r) acc[i][j][r] = 0.f;

    const int sr = tid >> 1;         // staging row 0..127
    const int sh = (tid & 1) * 16;   // staging k-offset 0 / 16

    for (int k0 = 0; k0 < K; k0 += BK) {
        short8 av0, av1;
        if (bm + sr < M) {
            const short8* ga = (const short8*)((const short*)A + (size_t)(bm + sr) * K + k0 + sh);
            av0 = ga[0];
            av1 = ga[1];
        } else {
#pragma unroll
            for (int i = 0; i < 8; ++i) { av0[i] = 0; av1[i] = 0; }
        }
        *(short8*)&As[sr * LDSP + sh]     = av0;
        *(short8*)&As[sr * LDSP + sh + 8] = av1;
        const short8* gb = (const short8*)((const short*)Bt + (size_t)(bn + sr) * K + k0 + sh);
        short8 bv0 = gb[0], bv1 = gb[1];
        *(short8*)&Bs[sr * LDSP + sh]     = bv0;
        *(short8*)&Bs[sr * LDSP + sh + 8] = bv1;
        __syncthreads();

        short8 af[4], bf[4];
#pragma unroll
        for (int mt = 0; mt < 4; ++mt)
            af[mt] = *(const short8*)&As[(wm + mt * 16 + l16) * LDSP + quad * 8];
#pragma unroll
        for (int nt = 0; nt < 4; ++nt)
            bf[nt] = *(const short8*)&Bs[(wn + nt * 16 + l16) * LDSP + quad * 8];
#pragma unroll
        for (int mt = 0; mt < 4; ++mt)
#pragma unroll
            for (int nt = 0; nt < 4; ++nt)
                acc[mt][nt] = __builtin_amdgcn_mfma_f32_16x16x32_bf16(
                    af[mt], bf[nt], acc[mt][nt], 0, 0, 0);
        __syncthreads();
    }

    if (!FUSE) {
#pragma unroll
        for (int mt = 0; mt < 4; ++mt) {
            const int row0 = bm + wm + mt * 16 + quad * 4;
#pragma unroll
            for (int nt = 0; nt < 4; ++nt) {
                const int col = bn + wn + nt * 16 + l16;
                const float bv = bias ? bias[col] : 0.f;
#pragma unroll
                for (int r = 0; r < 4; ++r) {
                    const int rr = row0 + r;
                    if (rr < M) {
                        float v = acc[mt][nt][r] + bv;
                        if (ACT == 1) v = v / (1.f + expf(-v));
                        C[(size_t)rr * N + col] = __float2bfloat16(v);
                    }
                }
            }
        }
    } else {
        float bv[4], wfv[4];
#pragma unroll
        for (int nt = 0; nt < 4; ++nt) {
            const int col = bn + wn + nt * 16 + l16;
            bv[nt]  = bias ? bias[col] : 0.f;
            wfv[nt] = Wf[col];
        }
#pragma unroll
        for (int mt = 0; mt < 4; ++mt) {
#pragma unroll
            for (int r = 0; r < 4; ++r) {
                const int row = bm + wm + mt * 16 + quad * 4 + r;
                float s = 0.f;
#pragma unroll
                for (int nt = 0; nt < 4; ++nt) {
                    float v = acc[mt][nt][r] + bv[nt];
                    if (ACT == 1) v = v / (1.f + expf(-v));
                    s = fmaf(v, wfv[nt], s);
                }
#pragma unroll
                for (int o = 8; o > 0; o >>= 1) s += __shfl_down(s, o);
                if (l16 == 0 && row < M) atomicAdd(&out[row], s);
            }
        }
    }
}

extern "C" void kernel_launch(void* const* d_in, const int* in_sizes, int n_in,
                              void* d_out, int out_size, void* d_ws, size_t ws_size,
                              hipStream_t stream) {
    const float* messages = (const float*)d_in[0];
    const float* rbf      = (const float*)d_in[1];
    const int*   idx_i    = (const int*)d_in[2];
    const float* W_rbf    = (const float*)d_in[3];
    const float* W_up     = (const float*)d_in[4];
    const float* W_d0     = (const float*)d_in[5];
    const float* b_d0     = (const float*)d_in[6];
    const float* W_d1     = (const float*)d_in[7];
    const float* b_d1     = (const float*)d_in[8];
    const float* W_final  = (const float*)d_in[9];
    float* out = (float*)d_out;

    char* ws = (char*)d_ws;
    __hip_bfloat16* summed = (__hip_bfloat16*)(ws + WS_SUMMED);
    __hip_bfloat16* buf0   = (__hip_bfloat16*)(ws + WS_BUF0);
    __hip_bfloat16* buf1   = (__hip_bfloat16*)(ws + WS_BUF1);
    __hip_bfloat16* wt_up  = (__hip_bfloat16*)(ws + WS_WTUP);
    __hip_bfloat16* wt_d0  = (__hip_bfloat16*)(ws + WS_WTD0);
    __hip_bfloat16* wt_d1  = (__hip_bfloat16*)(ws + WS_WTD1);
    int* cnt   = (int*)(ws + WS_CNT);
    int* cur   = (int*)(ws + WS_CUR);
    int* offp  = (int*)(ws + WS_OFF);
    int* elist = (int*)(ws + WS_ELIST);

    hipMemsetAsync(ws + WS_CNT, 0, 80000, stream);                 // cnt+cur
    hipMemsetAsync(d_out, 0, (size_t)N_PART * sizeof(float), stream);

    // CSR build
    hist_kernel<<<(N_EDGES_C + 255) / 256, 256, 0, stream>>>(idx_i, cnt);
    scan_kernel<<<1, 1024, 0, stream>>>(cnt, offp);
    fill_kernel<<<(N_EDGES_C + 255) / 256, 256, 0, stream>>>(idx_i, offp, cur, elist);

    // weight transpose+convert (one launch for all three)
    transpose_cvt_all<<<dim3(OUTE / 32, OUTE / 32, 3), 256, 0, stream>>>(
        W_up, W_d0, W_d1, wt_up, wt_d0, wt_d1);

    // gather (no atomics)
    gather_kernel<<<N_PART, 256, 0, stream>>>(messages, rbf, W_rbf, offp, cnt,
                                              elist, summed);

    // MLP via bf16 MFMA GEMMs; layer 3 fuses the W_final dot
    dim3 g((N_PART + BM - 1) / BM, OUTE / BN);  // 79 x 4
    gemm_mfma<0, 0><<<g, 256, 0, stream>>>(summed, wt_up, nullptr, buf0,
                                           nullptr, nullptr, N_PART, EMBED, OUTE);
    gemm_mfma<1, 0><<<g, 256, 0, stream>>>(buf0, wt_d0, b_d0, buf1,
                                           nullptr, nullptr, N_PART, OUTE, OUTE);
    gemm_mfma<1, 1><<<g, 256, 0, stream>>>(buf1, wt_d1, b_d1, nullptr,
                                           W_final, out, N_PART, OUTE, OUTE);
}